// Round 3
// baseline (494.298 us; speedup 1.0000x reference)
//
#include <hip/hip_runtime.h>

// Problem constants (VectorQuantizer: B=16, D=64, H=64, W=64, K=1024)
#define DD 64
#define KK 1024
#define NPTS 65536      // B*H*W
#define TOTAL 4194304   // B*D*H*W

// Output layout (concatenated flat, all read as float32 by harness)
#define OFF_L1 4194304
#define OFF_L2 4194305
#define OFF_IDX 4194306

// ws layout (floats): [0]=loss sum, [1]=block ticket counter,
// enorm @ +64 (1024 f), pval @ +2048 (2*65536 f), pidx @ +133120 (2*65536 f)
#define WS_ENORM 64
#define WS_PVAL 2048
#define WS_PIDX (2048 + 2 * NPTS)

// ---------------- kernel 1: codebook squared norms ----------------
__global__ __launch_bounds__(256) void enorm_kernel(const float* __restrict__ e,
                                                    float* __restrict__ enorm) {
    int k = blockIdx.x * 256 + threadIdx.x;
    if (k >= KK) return;
    float s = 0.f;
#pragma unroll
    for (int d = 0; d < DD; ++d) {
        float v = e[d * KK + k];
        s = fmaf(v, v, s);
    }
    enorm[k] = s;
}

// ---------------- kernel 2: partial argmin, K split in 2 halves ----------------
// Grid 2048: blockIdx & 1023 = point tile (64 pts), blockIdx >> 10 = k-half.
// Barrier-free K-loop: x tile in LDS (16 KB), e read directly from global (L2-hot).
// Thread micro-tile: 4 points x 8 codes; 4 k-tiles of 128 codes per half.
#define NT 64
#define KT 128

__global__ __launch_bounds__(256, 8) void argmin_part(const float* __restrict__ x,
                                                      const float* __restrict__ e,
                                                      const float* __restrict__ enorm,
                                                      float* __restrict__ pval,
                                                      float* __restrict__ pidx) {
    __shared__ __align__(16) float xs[DD * NT];   // [d][n], 16 KB; reused for reduce

    const int tid = threadIdx.x;
    const int tn4 = (tid & 15) * 4;
    const int tk = tid >> 4;          // 0..15
    const int tk8 = tk * 8;

    const int tile = blockIdx.x & 1023;
    const int kh = blockIdx.x >> 10;  // 0 or 1
    const int n0 = tile * NT;
    const int b = n0 >> 12;
    const int hw0 = n0 & 4095;
    const int kbase = kh * 512;

    // Stage x tile (once; the only barrier-protected phase).
    {
        const int j4 = (tid & 15) * 4;
        const int dbase = tid >> 4;   // 0..15
#pragma unroll
        for (int r = 0; r < 4; ++r) {
            const int d = r * 16 + dbase;
            *(float4*)(&xs[d * NT + j4]) =
                *(const float4*)(x + ((b * DD + d) << 12) + hw0 + j4);
        }
    }
    __syncthreads();

    float bv[4];
    int bi[4];
#pragma unroll
    for (int i = 0; i < 4; ++i) { bv[i] = 3.4e38f; bi[i] = 0; }

    for (int kt = 0; kt < 512 / KT; ++kt) {
        const int k0 = kbase + kt * KT;

        const float4 enA = *(const float4*)(enorm + k0 + tk8);
        const float4 enB = *(const float4*)(enorm + k0 + tk8 + 4);
        const float en[8] = {enA.x, enA.y, enA.z, enA.w, enB.x, enB.y, enB.z, enB.w};

        float acc[4][8];
#pragma unroll
        for (int i = 0; i < 4; ++i)
#pragma unroll
            for (int j = 0; j < 8; ++j) acc[i][j] = 0.f;

#pragma unroll 8
        for (int d = 0; d < DD; ++d) {
            const float4 xv = *(const float4*)(&xs[d * NT + tn4]);
            const float4 ea = *(const float4*)(e + d * KK + k0 + tk8);
            const float4 eb = *(const float4*)(e + d * KK + k0 + tk8 + 4);
            const float xa[4] = {xv.x, xv.y, xv.z, xv.w};
            const float ee[8] = {ea.x, ea.y, ea.z, ea.w, eb.x, eb.y, eb.z, eb.w};
#pragma unroll
            for (int i = 0; i < 4; ++i)
#pragma unroll
                for (int j = 0; j < 8; ++j)
                    acc[i][j] = fmaf(xa[i], ee[j], acc[i][j]);
        }

        // distances = ||e||^2 - 2*dot   (||x||^2 dropped; constant per point)
#pragma unroll
        for (int i = 0; i < 4; ++i) {
#pragma unroll
            for (int j = 0; j < 8; ++j) {
                const float dist = fmaf(-2.f, acc[i][j], en[j]);
                if (dist < bv[i]) { bv[i] = dist; bi[i] = k0 + tk8 + j; }
            }
        }
    }

    // Reduce 16 tk-partials per point; reuse xs.
    __syncthreads();
    float* rv = xs;           // [point][tk]
    float* ri = xs + 1024;
#pragma unroll
    for (int i = 0; i < 4; ++i) {
        const int p = tn4 + i;
        rv[p * 16 + tk] = bv[i];
        ri[p * 16 + tk] = (float)bi[i];
    }
    __syncthreads();
    if (tid < NT) {
        float best = rv[tid * 16];
        float bidx = ri[tid * 16];
#pragma unroll
        for (int t = 1; t < 16; ++t) {
            const float v = rv[tid * 16 + t];
            const float id = ri[tid * 16 + t];
            if (v < best || (v == best && id < bidx)) { best = v; bidx = id; }
        }
        pval[kh * NPTS + n0 + tid] = best;
        pidx[kh * NPTS + n0 + tid] = bidx;
    }
}

// ---------------- kernel 3: merge halves + gather + loss + finalize ----------------
// One block per (b,d): codebook row in LDS, merge the two k-half partials
// (cheap, redundant across d), gather quantized, block-reduced loss,
// ticket-based finalize by the last block.
__global__ __launch_bounds__(256) void merge_quant(const float* __restrict__ x,
                                                   const float* __restrict__ e,
                                                   const float* __restrict__ pval,
                                                   const float* __restrict__ pidx,
                                                   float* __restrict__ out,
                                                   float* __restrict__ sum,
                                                   unsigned* __restrict__ cnt) {
    __shared__ __align__(16) float es[KK];
    __shared__ float red[4];

    const int tid = threadIdx.x;
    const int b = blockIdx.x >> 6;
    const int d = blockIdx.x & 63;

    *(float4*)(&es[tid * 4]) = *(const float4*)(e + d * KK + tid * 4);
    __syncthreads();

    const float* xrow = x + ((b * DD + d) << 12);
    float* orow = out + ((b * DD + d) << 12);
    const float* pv0 = pval + (b << 12);
    const float* pv1 = pval + NPTS + (b << 12);
    const float* pi0 = pidx + (b << 12);
    const float* pi1 = pidx + NPTS + (b << 12);
    const bool writeidx = (d == 0);

    float acc = 0.f;
#pragma unroll
    for (int r = 0; r < 4; ++r) {
        const int j4 = (r * 256 + tid) * 4;
        const float4 v0 = *(const float4*)(pv0 + j4);
        const float4 v1 = *(const float4*)(pv1 + j4);
        const float4 i0 = *(const float4*)(pi0 + j4);
        const float4 i1 = *(const float4*)(pi1 + j4);
        // global tie -> smaller index: half0 wins ties (its indices are smaller)
        float4 kf;
        kf.x = (v1.x < v0.x) ? i1.x : i0.x;
        kf.y = (v1.y < v0.y) ? i1.y : i0.y;
        kf.z = (v1.z < v0.z) ? i1.z : i0.z;
        kf.w = (v1.w < v0.w) ? i1.w : i0.w;
        if (writeidx) {
            // OFF_IDX is only 8B-aligned -> scalar stores
            out[OFF_IDX + (b << 12) + j4 + 0] = kf.x;
            out[OFF_IDX + (b << 12) + j4 + 1] = kf.y;
            out[OFF_IDX + (b << 12) + j4 + 2] = kf.z;
            out[OFF_IDX + (b << 12) + j4 + 3] = kf.w;
        }
        const float4 xv = *(const float4*)(xrow + j4);
        const float q0 = es[(int)kf.x];
        const float q1 = es[(int)kf.y];
        const float q2 = es[(int)kf.z];
        const float q3 = es[(int)kf.w];
        float4 qv; qv.x = q0; qv.y = q1; qv.z = q2; qv.w = q3;
        *(float4*)(orow + j4) = qv;
        const float d0 = xv.x - q0, d1 = xv.y - q1, d2 = xv.z - q2, d3 = xv.w - q3;
        acc = fmaf(d0, d0, acc);
        acc = fmaf(d1, d1, acc);
        acc = fmaf(d2, d2, acc);
        acc = fmaf(d3, d3, acc);
    }

#pragma unroll
    for (int off = 32; off > 0; off >>= 1) acc += __shfl_down(acc, off, 64);
    if ((tid & 63) == 0) red[tid >> 6] = acc;
    __syncthreads();
    if (tid == 0) {
        atomicAdd(sum, red[0] + red[1] + red[2] + red[3]);
        __threadfence();
        const unsigned old = atomicAdd(cnt, 1u);
        if (old == (16 * 64 - 1)) {   // last block: all sums visible
            const float s = atomicAdd(sum, 0.0f);
            const float m = s * (1.0f / (float)TOTAL);
            out[OFF_L1] = m;
            out[OFF_L2] = m;
        }
    }
}

extern "C" void kernel_launch(void* const* d_in, const int* in_sizes, int n_in,
                              void* d_out, int out_size, void* d_ws, size_t ws_size,
                              hipStream_t stream) {
    const float* x = (const float*)d_in[0];      // [16,64,64,64]
    const float* e = (const float*)d_in[1];      // [64,1024]
    float* out = (float*)d_out;

    float* wsf = (float*)d_ws;
    float* sum = wsf;                            // [0]
    unsigned* cnt = (unsigned*)d_ws + 1;         // [1]
    float* enorm = wsf + WS_ENORM;
    float* pval = wsf + WS_PVAL;
    float* pidx = wsf + WS_PIDX;

    hipMemsetAsync(d_ws, 0, 8, stream);          // sum + ticket
    enorm_kernel<<<KK / 256, 256, 0, stream>>>(e, enorm);
    argmin_part<<<2048, 256, 0, stream>>>(x, e, enorm, pval, pidx);
    merge_quant<<<16 * 64, 256, 0, stream>>>(x, e, pval, pidx, out, sum, cnt);
}

// Round 4
// 266.199 us; speedup vs baseline: 1.8569x; 1.8569x over previous
//
#include <hip/hip_runtime.h>

// Problem constants (VectorQuantizer: B=16, D=64, H=64, W=64, K=1024)
#define DD 64
#define KK 1024
#define NPTS 65536      // B*H*W
#define TOTAL 4194304   // B*D*H*W

// Output layout (concatenated flat, all read as float32 by harness)
#define OFF_L1 4194304
#define OFF_L2 4194305
#define OFF_IDX 4194306

// ws layout (floats): [0]=loss sum, [1]=ticket, enorm @ +64, aligned idx @ +2048
#define WS_ENORM 64
#define WS_IDX 2048

// ---------------- kernel 1: codebook squared norms ----------------
__global__ __launch_bounds__(256) void enorm_kernel(const float* __restrict__ e,
                                                    float* __restrict__ enorm) {
    int k = blockIdx.x * 256 + threadIdx.x;
    if (k >= KK) return;
    float s = 0.f;
#pragma unroll
    for (int d = 0; d < DD; ++d) {
        float v = e[d * KK + k];
        s = fmaf(v, v, s);
    }
    enorm[k] = s;
}

// ---------------- kernel 2: fused distance-GEMM + argmin ----------------
// Block: 256 threads, tile 64 points x 128 codes, 8 k-tiles.
// Thread micro-tile: 4 points x 8 codes, codes split {tk*4+j, 64+tk*4+j}
// so each ds_read_b128 spans 256B across 16 lanes (2-way bank alias = free).
// e-tile is register double-buffered (prefetch k+1 during compute of k).
#define NT 64
#define KT 128

__global__ __launch_bounds__(256) void argmin_kernel(const float* __restrict__ x,
                                                     const float* __restrict__ e,
                                                     const float* __restrict__ enorm,
                                                     float* __restrict__ out_idx_f,
                                                     float* __restrict__ idx_aligned) {
    __shared__ __align__(16) float xs[DD * NT];   // 16 KB
    __shared__ __align__(16) float es[DD * KT];   // 32 KB (reused for reduction)

    const int tid = threadIdx.x;
    const int tn4 = (tid & 15) * 4;
    const int tk = tid >> 4;          // 0..15
    const int tk4 = tk * 4;

    const int n0 = blockIdx.x * NT;
    const int b = n0 >> 12;
    const int hw0 = n0 & 4095;

    // Staging decomposition for e-tile (contiguous 1KB per wave -> conflict-free)
    const int sd = tid >> 5;          // 0..7
    const int sc = (tid & 31) * 4;    // 0..124

    // Stage x tile: xs[d][j] (conflict-free contiguous writes)
    {
        const int j4 = (tid & 15) * 4;
        const int dbase = tid >> 4;
#pragma unroll
        for (int r = 0; r < 4; ++r) {
            const int d = r * 16 + dbase;
            *(float4*)(&xs[d * NT + j4]) =
                *(const float4*)(x + ((b * DD + d) << 12) + hw0 + j4);
        }
    }

    // Prefetch e-tile 0 into registers
    float4 pf[8];
#pragma unroll
    for (int r = 0; r < 8; ++r)
        pf[r] = *(const float4*)(e + (r * 8 + sd) * KK + sc);

    float bv[4];
    int bi[4];
#pragma unroll
    for (int i = 0; i < 4; ++i) { bv[i] = 3.4e38f; bi[i] = 0; }

    for (int kt = 0; kt < KK / KT; ++kt) {
        const int k0 = kt * KT;

        if (kt) __syncthreads();     // prior tile's readers done
        // store prefetched tile to LDS
#pragma unroll
        for (int r = 0; r < 8; ++r)
            *(float4*)(&es[(r * 8 + sd) * KT + sc]) = pf[r];
        __syncthreads();

        // issue next tile's global loads early (overlap with compute)
        if (kt < KK / KT - 1) {
#pragma unroll
            for (int r = 0; r < 8; ++r)
                pf[r] = *(const float4*)(e + (r * 8 + sd) * KK + k0 + KT + sc);
        }

        // e-norms for this thread's 8 codes (issued early, used at tile end)
        const float4 enA = *(const float4*)(enorm + k0 + tk4);
        const float4 enB = *(const float4*)(enorm + k0 + 64 + tk4);

        float acc[4][8];
#pragma unroll
        for (int i = 0; i < 4; ++i)
#pragma unroll
            for (int j = 0; j < 8; ++j) acc[i][j] = 0.f;

#pragma unroll 8
        for (int d = 0; d < DD; ++d) {
            const float4 xv = *(const float4*)(&xs[d * NT + tn4]);
            const float4 ea = *(const float4*)(&es[d * KT + tk4]);        // codes k0+tk4+j
            const float4 eb = *(const float4*)(&es[d * KT + 64 + tk4]);   // codes k0+64+tk4+j
            const float xa[4] = {xv.x, xv.y, xv.z, xv.w};
            const float ee[8] = {ea.x, ea.y, ea.z, ea.w, eb.x, eb.y, eb.z, eb.w};
#pragma unroll
            for (int i = 0; i < 4; ++i)
#pragma unroll
                for (int j = 0; j < 8; ++j)
                    acc[i][j] = fmaf(xa[i], ee[j], acc[i][j]);
        }

        const float en[8] = {enA.x, enA.y, enA.z, enA.w, enB.x, enB.y, enB.z, enB.w};
        const int kidx[8] = {k0 + tk4, k0 + tk4 + 1, k0 + tk4 + 2, k0 + tk4 + 3,
                             k0 + 64 + tk4, k0 + 64 + tk4 + 1,
                             k0 + 64 + tk4 + 2, k0 + 64 + tk4 + 3};
#pragma unroll
        for (int i = 0; i < 4; ++i) {
#pragma unroll
            for (int j = 0; j < 8; ++j) {
                const float dist = fmaf(-2.f, acc[i][j], en[j]);
                // strict <: earliest (smallest) index wins ties; kidx ascends
                // within each group and groups/tiles ascend in k for fixed tk,
                // cross-tk ties handled in the final reduction.
                if (dist < bv[i]) { bv[i] = dist; bi[i] = kidx[j]; }
            }
        }
    }

    // Cross-thread reduction over tk (16 partials per point), reuse es.
    __syncthreads();
    float* rv = es;
    float* ri = es + 1024;
#pragma unroll
    for (int i = 0; i < 4; ++i) {
        const int p = tn4 + i;
        rv[p * 16 + tk] = bv[i];
        ri[p * 16 + tk] = (float)bi[i];
    }
    __syncthreads();
    if (tid < NT) {
        float best = rv[tid * 16];
        float bidx = ri[tid * 16];
#pragma unroll
        for (int t = 1; t < 16; ++t) {
            const float v = rv[tid * 16 + t];
            const float id = ri[tid * 16 + t];
            if (v < best || (v == best && id < bidx)) { best = v; bidx = id; }
        }
        out_idx_f[n0 + tid] = bidx;
        idx_aligned[n0 + tid] = bidx;
    }
}

// ---------------- kernel 3: gather + loss + finalize (ticketed) ----------------
__global__ __launch_bounds__(256) void quant_loss(const float* __restrict__ x,
                                                  const float* __restrict__ e,
                                                  const float* __restrict__ idxf,
                                                  float* __restrict__ out,
                                                  float* __restrict__ sum,
                                                  unsigned* __restrict__ cnt) {
    __shared__ __align__(16) float es[KK];
    __shared__ float red[4];

    const int tid = threadIdx.x;
    const int b = blockIdx.x >> 6;
    const int d = blockIdx.x & 63;

    *(float4*)(&es[tid * 4]) = *(const float4*)(e + d * KK + tid * 4);
    __syncthreads();

    const float* xrow = x + ((b * DD + d) << 12);
    float* orow = out + ((b * DD + d) << 12);
    const float* irow = idxf + (b << 12);

    float acc = 0.f;
#pragma unroll
    for (int r = 0; r < 4; ++r) {
        const int j4 = (r * 256 + tid) * 4;
        const float4 xv = *(const float4*)(xrow + j4);
        const float4 kf = *(const float4*)(irow + j4);
        const float q0 = es[(int)kf.x];
        const float q1 = es[(int)kf.y];
        const float q2 = es[(int)kf.z];
        const float q3 = es[(int)kf.w];
        float4 qv; qv.x = q0; qv.y = q1; qv.z = q2; qv.w = q3;
        *(float4*)(orow + j4) = qv;
        const float d0 = xv.x - q0, d1 = xv.y - q1, d2 = xv.z - q2, d3 = xv.w - q3;
        acc = fmaf(d0, d0, acc);
        acc = fmaf(d1, d1, acc);
        acc = fmaf(d2, d2, acc);
        acc = fmaf(d3, d3, acc);
    }

#pragma unroll
    for (int off = 32; off > 0; off >>= 1) acc += __shfl_down(acc, off, 64);
    if ((tid & 63) == 0) red[tid >> 6] = acc;
    __syncthreads();
    if (tid == 0) {
        atomicAdd(sum, red[0] + red[1] + red[2] + red[3]);
        __threadfence();
        const unsigned old = atomicAdd(cnt, 1u);
        if (old == (16 * 64 - 1)) {
            const float s = atomicAdd(sum, 0.0f);
            const float m = s * (1.0f / (float)TOTAL);
            out[OFF_L1] = m;   // dictionary_loss
            out[OFF_L2] = m;   // commitment_loss (numerically identical)
        }
    }
}

extern "C" void kernel_launch(void* const* d_in, const int* in_sizes, int n_in,
                              void* d_out, int out_size, void* d_ws, size_t ws_size,
                              hipStream_t stream) {
    const float* x = (const float*)d_in[0];      // [16,64,64,64]
    const float* e = (const float*)d_in[1];      // [64,1024]
    float* out = (float*)d_out;

    float* wsf = (float*)d_ws;
    float* sum = wsf;                            // [0]
    unsigned* cnt = (unsigned*)d_ws + 1;         // [1]
    float* enorm = wsf + WS_ENORM;
    float* idxa = wsf + WS_IDX;                  // aligned idx copy (float values)

    hipMemsetAsync(d_ws, 0, 8, stream);          // sum + ticket
    enorm_kernel<<<KK / 256, 256, 0, stream>>>(e, enorm);
    argmin_kernel<<<NPTS / NT, 256, 0, stream>>>(x, e, enorm, out + OFF_IDX, idxa);
    quant_loss<<<16 * 64, 256, 0, stream>>>(x, e, idxa, out, sum, cnt);
}

// Round 5
// 203.929 us; speedup vs baseline: 2.4239x; 1.3053x over previous
//
#include <hip/hip_runtime.h>

// Problem constants (VectorQuantizer: B=16, D=64, H=64, W=64, K=1024)
#define DD 64
#define KK 1024
#define NPTS 65536      // B*H*W
#define TOTAL 4194304   // B*D*H*W

// Output layout (concatenated flat, all read as float32 by harness)
#define OFF_L1 4194304
#define OFF_L2 4194305
#define OFF_IDX 4194306

#define WS_ENORM 64     // ws float offset of enorm[1024]

#define NT 128          // points per block
#define KT 128          // codes per k-tile
#define NBLK (NPTS / NT) // 512

// ---------------- kernel 1: codebook squared norms ----------------
__global__ __launch_bounds__(256) void enorm_kernel(const float* __restrict__ e,
                                                    float* __restrict__ enorm) {
    int k = blockIdx.x * 256 + threadIdx.x;
    if (k >= KK) return;
    float s = 0.f;
#pragma unroll
    for (int d = 0; d < DD; ++d) {
        float v = e[d * KK + k];
        s = fmaf(v, v, s);
    }
    enorm[k] = s;
}

// ---------------- kernel 2: fused argmin + quantize + loss ----------------
// Block: 256 threads, tile 128 points x full K (8 k-tiles of 128 codes).
// Micro-tile 8 pts x 8 codes: per d-iter 4 ds_read_b128 per 64 FMA ->
// LDS pipe (4*8cy*4waves=128cy/CU) == VALU (64FMA*2cy=128cy) balanced.
// After argmin: gather chosen codes from global e (L2-hot), write quantized
// + indices, block-reduce loss, ticket-based finalize.
__global__ __launch_bounds__(256) void vq_mega(const float* __restrict__ x,
                                               const float* __restrict__ e,
                                               const float* __restrict__ enorm,
                                               float* __restrict__ out,
                                               float* __restrict__ sum,
                                               unsigned* __restrict__ cnt) {
    __shared__ __align__(16) float xs[DD * NT];   // 32 KB  [d][pt]
    __shared__ __align__(16) float es[DD * KT];   // 32 KB  [d][kk]; reused for reduce
    __shared__ int ks[NT];                         // chosen code per point
    __shared__ float red[4];

    const int tid = threadIdx.x;
    const int tn8 = (tid & 15) * 8;   // point group base (8 pts)
    const int tk = tid >> 4;          // 0..15
    const int tk4 = tk * 4;           // codes {k0+tk4+j, k0+64+tk4+j}

    const int n0 = blockIdx.x * NT;
    const int b = n0 >> 12;
    const int hw0 = n0 & 4095;

    // staging decomposition: 8 rows per thread, contiguous 512B per 32 lanes
    const int sd = tid >> 5;          // 0..7
    const int sc = (tid & 31) * 4;    // 0..124

    // ---- stage x tile: xs[d][p] ----
#pragma unroll
    for (int r = 0; r < 8; ++r) {
        const int d = r * 8 + sd;
        *(float4*)(&xs[d * NT + sc]) =
            *(const float4*)(x + ((b * DD + d) << 12) + hw0 + sc);
    }

    float bv[8];
    int bi[8];
#pragma unroll
    for (int i = 0; i < 8; ++i) { bv[i] = 3.4e38f; bi[i] = 0; }

    for (int kt = 0; kt < KK / KT; ++kt) {
        const int k0 = kt * KT;

        if (kt) __syncthreads();   // prior tile's readers done (also covers xs stage)
        else __syncthreads();
        // ---- stage e tile: es[d][kk] ----
#pragma unroll
        for (int r = 0; r < 8; ++r) {
            const int d = r * 8 + sd;
            *(float4*)(&es[d * KT + sc]) = *(const float4*)(e + d * KK + k0 + sc);
        }
        __syncthreads();

        const float4 enA = *(const float4*)(enorm + k0 + tk4);
        const float4 enB = *(const float4*)(enorm + k0 + 64 + tk4);

        float acc[8][8];
#pragma unroll
        for (int i = 0; i < 8; ++i)
#pragma unroll
            for (int j = 0; j < 8; ++j) acc[i][j] = 0.f;

#pragma unroll 8
        for (int d = 0; d < DD; ++d) {
            const float4 x0 = *(const float4*)(&xs[d * NT + tn8]);
            const float4 x1 = *(const float4*)(&xs[d * NT + tn8 + 4]);
            const float4 e0 = *(const float4*)(&es[d * KT + tk4]);
            const float4 e1 = *(const float4*)(&es[d * KT + 64 + tk4]);
            const float xa[8] = {x0.x, x0.y, x0.z, x0.w, x1.x, x1.y, x1.z, x1.w};
            const float ee[8] = {e0.x, e0.y, e0.z, e0.w, e1.x, e1.y, e1.z, e1.w};
#pragma unroll
            for (int i = 0; i < 8; ++i)
#pragma unroll
                for (int j = 0; j < 8; ++j)
                    acc[i][j] = fmaf(xa[i], ee[j], acc[i][j]);
        }

        const float en[8] = {enA.x, enA.y, enA.z, enA.w, enB.x, enB.y, enB.z, enB.w};
#pragma unroll
        for (int i = 0; i < 8; ++i) {
#pragma unroll
            for (int j = 0; j < 8; ++j) {
                const float dist = fmaf(-2.f, acc[i][j], en[j]);
                const int kj = (j < 4) ? (k0 + tk4 + j) : (k0 + 64 + tk4 + j - 4);
                // strict <: this thread's codes ascend in k across j-groups/tiles
                if (dist < bv[i]) { bv[i] = dist; bi[i] = kj; }
            }
        }
    }

    // ---- cross-thread argmin reduce (16 tk-partials per point), reuse es ----
    __syncthreads();
    float* rv = es;              // [pt][tk] stride 17 (conflict-free final reads)
    float* ri = es + NT * 17;    // 2176 + 2176 floats <= 8192 ok
#pragma unroll
    for (int i = 0; i < 8; ++i) {
        const int p = tn8 + i;
        rv[p * 17 + tk] = bv[i];
        ri[p * 17 + tk] = (float)bi[i];
    }
    __syncthreads();
    if (tid < NT) {
        float best = rv[tid * 17];
        float bidx = ri[tid * 17];
#pragma unroll
        for (int t = 1; t < 16; ++t) {
            const float v = rv[tid * 17 + t];
            const float id = ri[tid * 17 + t];
            if (v < best || (v == best && id < bidx)) { best = v; bidx = id; }
        }
        const int k = (int)bidx;
        ks[tid] = k;
        out[OFF_IDX + n0 + tid] = bidx;
    }
    __syncthreads();

    // ---- fused quantize + loss: thread (p, d-half) ----
    const int p = tid & 127;
    const int dh = tid >> 7;     // 0 or 1
    const int kp = ks[p];
    float lacc = 0.f;
#pragma unroll 8
    for (int dd = 0; dd < 32; ++dd) {
        const int d = dh * 32 + dd;
        const float q = e[d * KK + kp];               // scattered, L2-hot
        const float xv = xs[d * NT + p];
        out[((b * DD + d) << 12) + hw0 + p] = q;
        const float df = xv - q;
        lacc = fmaf(df, df, lacc);
    }

#pragma unroll
    for (int off = 32; off > 0; off >>= 1) lacc += __shfl_down(lacc, off, 64);
    if ((tid & 63) == 0) red[tid >> 6] = lacc;
    __syncthreads();
    if (tid == 0) {
        atomicAdd(sum, red[0] + red[1] + red[2] + red[3]);
        __threadfence();
        const unsigned old = atomicAdd(cnt, 1u);
        if (old == (NBLK - 1)) {            // last block: all sums visible
            const float s = atomicAdd(sum, 0.0f);
            const float m = s * (1.0f / (float)TOTAL);
            out[OFF_L1] = m;   // dictionary_loss
            out[OFF_L2] = m;   // commitment_loss (numerically identical)
        }
    }
}

extern "C" void kernel_launch(void* const* d_in, const int* in_sizes, int n_in,
                              void* d_out, int out_size, void* d_ws, size_t ws_size,
                              hipStream_t stream) {
    const float* x = (const float*)d_in[0];      // [16,64,64,64]
    const float* e = (const float*)d_in[1];      // [64,1024]
    float* out = (float*)d_out;

    float* wsf = (float*)d_ws;
    float* sum = wsf;                            // [0]
    unsigned* cnt = (unsigned*)d_ws + 1;         // [1]
    float* enorm = wsf + WS_ENORM;

    hipMemsetAsync(d_ws, 0, 8, stream);          // sum + ticket
    enorm_kernel<<<KK / 256, 256, 0, stream>>>(e, enorm);
    vq_mega<<<NBLK, 256, 0, stream>>>(x, e, enorm, out, sum, cnt);
}